// Round 13
// baseline (461.220 us; speedup 1.0000x reference)
//
#include <hip/hip_runtime.h>
#include <hip/hip_bf16.h>

#define NN 50000
#define EE 600000
#define HH 128
#define OUTD 32
#define RR 64
#define BB 16
#define KK 2048   // BB*HH
#define SC_B ((NN + 1023) / 1024)  // 49 scan chunks
#define N_CONVW ((HH + OUTD) * KK)
#define N_EMB   (NN * HH / 2)

typedef short s16x8 __attribute__((ext_vector_type(8)));
typedef float f32x4 __attribute__((ext_vector_type(4)));
typedef float f32x2 __attribute__((ext_vector_type(2)));
typedef unsigned short ushort_t;
typedef unsigned int uint_t;
typedef __attribute__((address_space(3))) uint_t lds_u32;
typedef const __attribute__((address_space(1))) uint_t glb_u32;

__device__ inline ushort_t f_to_bf16(float f){
    __hip_bfloat16 h = __float2bfloat16(f);
    return *reinterpret_cast<ushort_t*>(&h);
}
__device__ inline uint_t pack_bf16x2(float a, float b){
    return (uint_t)f_to_bf16(a) | ((uint_t)f_to_bf16(b) << 16);
}

__global__ void hist_kernel(const int* __restrict__ dst, int* counts){
    int e = blockIdx.x*256 + threadIdx.x;
    if (e < EE) atomicAdd(&counts[dst[e]], 1);
}

// ---- hierarchical scan: chunk totals -> scan totals -> final ----
__global__ void scan_part(const int* __restrict__ counts, int* __restrict__ tot){
    int b = blockIdx.x, t = threadIdx.x;
    int i0 = b*1024 + t*4;
    int s = 0;
    if (i0 + 3 < NN){
        int4 v = *reinterpret_cast<const int4*>(&counts[i0]);
        s = v.x + v.y + v.z + v.w;
    } else {
        for (int j = 0; j < 4; j++) if (i0 + j < NN) s += counts[i0 + j];
    }
    #pragma unroll
    for (int off = 32; off; off >>= 1) s += __shfl_xor(s, off, 64);
    __shared__ int ws[4];
    if ((t & 63) == 0) ws[t >> 6] = s;
    __syncthreads();
    if (t == 0) tot[b] = ws[0] + ws[1] + ws[2] + ws[3];
}

__global__ void scan_tot(int* tot){  // 1 block, 64 threads (SC_B <= 64)
    int t = threadIdx.x;
    int v = (t < SC_B) ? tot[t] : 0;
    int x = v;
    #pragma unroll
    for (int off = 1; off < 64; off <<= 1){
        int y = __shfl_up(x, off, 64);
        if (t >= off) x += y;
    }
    if (t < SC_B) tot[t] = x - v;  // exclusive base per chunk
}

__global__ void scan_final(const int* __restrict__ counts, const int* __restrict__ tot,
                           int* __restrict__ offsets, int* __restrict__ cursor){
    int b = blockIdx.x, t = threadIdx.x, lane = t & 63, wv = t >> 6;
    int i0 = b*1024 + t*4;
    int v[4]; int s = 0;
    #pragma unroll
    for (int j = 0; j < 4; j++){ v[j] = (i0 + j < NN) ? counts[i0 + j] : 0; s += v[j]; }
    int x = s;
    #pragma unroll
    for (int off = 1; off < 64; off <<= 1){
        int y = __shfl_up(x, off, 64);
        if (lane >= off) x += y;
    }
    __shared__ int ws[4];
    if (lane == 63) ws[wv] = x;
    __syncthreads();
    int pre = tot[b];
    for (int i = 0; i < wv; i++) pre += ws[i];
    int run = pre + x - s;  // exclusive start of this thread's 4 elems
    #pragma unroll
    for (int j = 0; j < 4; j++){
        if (i0 + j < NN){
            cursor[i0 + j] = run;
            offsets[i0 + j + 1] = run + v[j];
        }
        run += v[j];
    }
    if (b == 0 && t == 0) offsets[0] = 0;
}

// scatter dst-sorted edge payload: msrc[r] = src row, netn[r] = norm_bits|etype
// (etype stuffed into norm's 6 low mantissa bits: <=7.5e-6 relative error)
__global__ void scatter_kernel(const int* __restrict__ dst, const int* __restrict__ src,
                               const int* __restrict__ etype, const float* __restrict__ norm,
                               int* cursor, int* __restrict__ msrc, int* __restrict__ netn){
    int e = blockIdx.x*256 + threadIdx.x;
    if (e >= EE) return;
    int d = dst[e];
    int r = atomicAdd(&cursor[d], 1);
    msrc[r] = src[e];
    netn[r] = (__float_as_int(norm[e]) & ~63) | etype[e];
}

// per-edge weight vector wedge[e][0..15] = comp[etype_e] * norm_e (coalesced)
__device__ inline void build_w_one(int e, const int* __restrict__ netn,
                                   const float* __restrict__ comp,
                                   float* __restrict__ wedge){
    int nb = netn[e];
    int et = nb & 63;
    float nw = __int_as_float(nb & ~63);
    const float4* c = reinterpret_cast<const float4*>(comp + et*BB);
    float4* wp = reinterpret_cast<float4*>(wedge + (size_t)e*BB);
    #pragma unroll
    for (int q = 0; q < 4; q++){
        float4 cv = c[q];
        wp[q] = make_float4(cv.x*nw, cv.y*nw, cv.z*nw, cv.w*nw);
    }
}

__global__ void build_w_kernel(const int* __restrict__ netn, const float* __restrict__ comp,
                               float* __restrict__ wedge){
    int e = blockIdx.x*256 + threadIdx.x;
    if (e < EE) build_w_one(e, netn, comp, wedge);
}

// fused prologue: Wt1/Wt2 transpose-convert, emb->bf16, wedge (layer 1)
__global__ void prep_kernel(const float* __restrict__ V1, const float* __restrict__ V2,
                            const float* __restrict__ emb, const int* __restrict__ netn,
                            const float* __restrict__ comp1,
                            ushort_t* __restrict__ Wt1, ushort_t* __restrict__ Wt2,
                            ushort_t* __restrict__ xb, float* __restrict__ wedge){
    int i = blockIdx.x*256 + threadIdx.x;
    if (i < HH*KK){
        int o = i / KK, k = i % KK;
        Wt1[i] = f_to_bf16(V1[(size_t)k*HH + o]);
    } else if (i < N_CONVW){
        int j = i - HH*KK;
        int o = j / KK, k = j % KK;
        Wt2[j] = f_to_bf16(V2[(size_t)k*OUTD + o]);
    } else if (i < N_CONVW + N_EMB){
        int j = i - N_CONVW;
        float2 f = *reinterpret_cast<const float2*>(emb + 2*(size_t)j);
        *reinterpret_cast<uint_t*>(xb + 2*(size_t)j) = pack_bf16x2(f.x, f.y);
    } else {
        int e = i - N_CONVW - N_EMB;
        if (e < EE) build_w_one(e, netn, comp1, wedge);
    }
}

// Aggregate: 1 node per wave, 4 waves/block, no LDS/barriers. Per <=64-edge
// chunk: src rows in lane registers; 8-deep register ring of coalesced 256B
// x-row loads; per edge: 2 unpack + 16 v_pk_fma_f32 with weight pairs from
// uniform s_load_dwordx16 of the precomputed wedge (norm folded in).
__global__ __launch_bounds__(256, 8) void agg_kernel(
    const ushort_t* __restrict__ xin, const int* __restrict__ msrc,
    const float* __restrict__ wedge, const int* __restrict__ offsets,
    ushort_t* __restrict__ agg, int v0, int vc)
{
    int w = threadIdx.x >> 6, lane = threadIdx.x & 63;
    int v = v0 + blockIdx.x*4 + w;
    if (v >= v0 + vc) return;
    int p0 = offsets[v];
    int dd = offsets[v+1] - p0;
    const uint_t* xrow = reinterpret_cast<const uint_t*>(xin);  // row r at xrow + r*64

    // accA[bp] = {agg[2bp], agg[2bp+1]} at feat 2*lane; accB at feat 2*lane+1
    f32x2 accA[8], accB[8];
    #pragma unroll
    for (int bp = 0; bp < 8; bp++){
        accA[bp].x = 0.f; accA[bp].y = 0.f;
        accB[bp].x = 0.f; accB[bp].y = 0.f;
    }

    for (int c0 = 0; c0 < dd; c0 += 64){
        int nc = min(64, dd - c0);
        int sp = __builtin_amdgcn_readfirstlane(p0 + c0);
        int mp = msrc[sp + min(lane, nc - 1)];   // lane e: src row of edge e
        uint_t xr[8];
        #pragma unroll
        for (int j = 0; j < 8; ++j){
            int sr = __builtin_amdgcn_readlane(mp, min(j, nc - 1));
            xr[j] = xrow[(size_t)sr*64 + lane];
        }
        const f32x2* wb = reinterpret_cast<const f32x2*>(wedge) + (size_t)sp*8;
        int ebf = nc & ~7;   // full 8-groups
        for (int eb = 0; eb < ebf; eb += 8){
            #pragma unroll
            for (int j = 0; j < 8; ++j){
                int e = eb + j;                       // uniform
                uint_t u = xr[j];
                f32x2 xs;
                xs.x = __uint_as_float(u << 16);          // feat 2*lane
                xs.y = __uint_as_float(u & 0xffff0000u);  // feat 2*lane+1
                int en = e + 8;
                if (en < nc){                          // uniform branch: refill ring
                    int srn = __builtin_amdgcn_readlane(mp, en);
                    xr[j] = xrow[(size_t)srn*64 + lane];
                }
                const f32x2* cp = wb + (size_t)e*8;    // uniform -> s_load_dwordx16
                #pragma unroll
                for (int bp = 0; bp < 8; bp++){
                    f32x2 c2 = cp[bp];   // {w[2bp], w[2bp+1]} consecutive SGPRs
                    asm("v_pk_fma_f32 %0, %1, %2, %0 op_sel:[0,0,0] op_sel_hi:[1,0,1]"
                        : "+v"(accA[bp]) : "s"(c2), "v"(xs));
                    asm("v_pk_fma_f32 %0, %1, %2, %0 op_sel:[0,1,0] op_sel_hi:[1,1,1]"
                        : "+v"(accB[bp]) : "s"(c2), "v"(xs));
                }
            }
        }
        // tail (< 8 edges): statically unrolled, uniform guard, xr index static
        #pragma unroll
        for (int j = 0; j < 8; ++j){
            int e = ebf + j;
            if (e < nc){
                uint_t u = xr[j];       // e & 7 == j (ebf % 8 == 0)
                f32x2 xs;
                xs.x = __uint_as_float(u << 16);
                xs.y = __uint_as_float(u & 0xffff0000u);
                const f32x2* cp = wb + (size_t)e*8;
                #pragma unroll
                for (int bp = 0; bp < 8; bp++){
                    f32x2 c2 = cp[bp];
                    asm("v_pk_fma_f32 %0, %1, %2, %0 op_sel:[0,0,0] op_sel_hi:[1,0,1]"
                        : "+v"(accA[bp]) : "s"(c2), "v"(xs));
                    asm("v_pk_fma_f32 %0, %1, %2, %0 op_sel:[0,1,0] op_sel_hi:[1,1,1]"
                        : "+v"(accB[bp]) : "s"(c2), "v"(xs));
                }
            }
        }
    }
    // store agg row (bf16x2 packed, coalesced 256B per basis)
    uint_t* arow = reinterpret_cast<uint_t*>(agg) + (size_t)(v - v0)*1024 + lane;
    #pragma unroll
    for (int b = 0; b < BB; b++)
        arow[b*64] = pack_bf16x2(accA[b>>1][b&1], accB[b>>1][b&1]);
}

// GEMM: C[m, o] = sum_k A[m,k] * Wt[o,k] (+bias, opt relu). 128xBN tile, 512
// thr. Double-buffered global_load_lds staging w/ chunk-XOR swizzle; COUNTED
// vmcnt at a raw s_barrier (prefetch loads stay in flight across the barrier).
template<int BN, bool RELU, bool OUT_BF16>
__global__ __launch_bounds__(512, 4) void gemm_kernel(
    const ushort_t* __restrict__ A, const ushort_t* __restrict__ Wt,
    const float* __restrict__ bias, void* __restrict__ yout, int vc)
{
    __shared__ __align__(16) char Ald[2][128*128];
    __shared__ __align__(16) char Bld[2][BN*128];
    constexpr int RT = (BN == 128) ? 2 : 1;
    constexpr int CT = (BN == 128) ? 4 : 2;
    constexpr int NT = KK / 64;
    int tid = threadIdx.x, lane = tid & 63, lane15 = lane & 15;
    int w = tid >> 6;
    int wrbase = (BN == 128) ? (w >> 1)*32 : w*16;
    int wcbase = (BN == 128) ? (w & 1)*64 : 0;
    int m0 = blockIdx.x * 128;

    int rl = lane >> 3, jl = lane & 7;
    int ra0 = w*2*8 + rl,  ra1 = (w*2+1)*8 + rl;
    const ushort_t* agp0 = A + (size_t)(m0 + min(ra0, vc-1))*KK + ((jl ^ (ra0 & 7))*8);
    const ushort_t* agp1 = A + (size_t)(m0 + min(ra1, vc-1))*KK + ((jl ^ (ra1 & 7))*8);
    const ushort_t* bgp0;
    const ushort_t* bgp1;
    if (BN == 128){
        bgp0 = Wt + (size_t)ra0*KK + ((jl ^ (ra0 & 7))*8);
        bgp1 = Wt + (size_t)ra1*KK + ((jl ^ (ra1 & 7))*8);
    } else {
        int rb = w*8 + rl;  // valid for w<4
        bgp0 = Wt + (size_t)min(rb, BN-1)*KK + ((jl ^ (rb & 7))*8);
        bgp1 = nullptr;
    }

    auto stage = [&](int buf){
        __builtin_amdgcn_global_load_lds((glb_u32*)agp0,
            (lds_u32*)(&Ald[buf][(w*2+0)*1024]), 16, 0, 0);
        __builtin_amdgcn_global_load_lds((glb_u32*)agp1,
            (lds_u32*)(&Ald[buf][(w*2+1)*1024]), 16, 0, 0);
        agp0 += 64; agp1 += 64;
        if constexpr (BN == 128){
            __builtin_amdgcn_global_load_lds((glb_u32*)bgp0,
                (lds_u32*)(&Bld[buf][(w*2+0)*1024]), 16, 0, 0);
            __builtin_amdgcn_global_load_lds((glb_u32*)bgp1,
                (lds_u32*)(&Bld[buf][(w*2+1)*1024]), 16, 0, 0);
            bgp0 += 64; bgp1 += 64;
        } else {
            if (w < 4){
                __builtin_amdgcn_global_load_lds((glb_u32*)bgp0,
                    (lds_u32*)(&Bld[buf][w*1024]), 16, 0, 0);
                bgp0 += 64;
            }
        }
    };

    f32x4 acc[RT][CT];
    #pragma unroll
    for (int t = 0; t < RT; t++)
        #pragma unroll
        for (int ct = 0; ct < CT; ct++)
            #pragma unroll
            for (int j = 0; j < 4; j++) acc[t][ct][j] = 0.f;

    auto compute = [&](int buf){
        #pragma unroll
        for (int ks = 0; ks < 2; ks++){
            int csw = (ks*4 + (lane >> 4)) ^ (lane15 & 7);
            #pragma unroll
            for (int t = 0; t < RT; t++){
                int arow = wrbase + t*16 + lane15;
                s16x8 a = *reinterpret_cast<const s16x8*>(&Ald[buf][arow*128 + csw*16]);
                #pragma unroll
                for (int ct = 0; ct < CT; ct++){
                    int brow = wcbase + ct*16 + lane15;
                    s16x8 b = *reinterpret_cast<const s16x8*>(&Bld[buf][brow*128 + csw*16]);
                    acc[t][ct] = __builtin_amdgcn_mfma_f32_16x16x32_bf16(a, b, acc[t][ct], 0,0,0);
                }
            }
        }
    };

    stage(0);
    for (int t = 0; t < NT; ++t){
        int cur = t & 1;
        if (t + 1 < NT){
            stage(cur ^ 1);
            if (BN == 128)       asm volatile("s_waitcnt vmcnt(4)" ::: "memory");
            else if (w < 4)      asm volatile("s_waitcnt vmcnt(3)" ::: "memory");
            else                 asm volatile("s_waitcnt vmcnt(2)" ::: "memory");
        } else {
            asm volatile("s_waitcnt vmcnt(0)" ::: "memory");
        }
        __builtin_amdgcn_s_barrier();
        __builtin_amdgcn_sched_barrier(0);
        compute(cur);
        __builtin_amdgcn_s_barrier();
    }

    #pragma unroll
    for (int t = 0; t < RT; t++){
        int rb = m0 + wrbase + t*16 + ((lane >> 4) << 2);
        #pragma unroll
        for (int ct = 0; ct < CT; ct++){
            int col = wcbase + ct*16 + lane15;
            float bv = bias[col];
            #pragma unroll
            for (int r = 0; r < 4; r++){
                int row = rb + r;
                if (row < vc){
                    float val = acc[t][ct][r] + bv;
                    if (RELU) val = fmaxf(val, 0.f);
                    if (OUT_BF16)
                        reinterpret_cast<ushort_t*>(yout)[(size_t)row*BN + col] = f_to_bf16(val);
                    else
                        reinterpret_cast<float*>(yout)[(size_t)row*BN + col] = val;
                }
            }
        }
    }
}

extern "C" void kernel_launch(void* const* d_in, const int* in_sizes, int n_in,
                              void* d_out, int out_size, void* d_ws, size_t ws_size,
                              hipStream_t stream){
    const int*   src   = (const int*)d_in[0];
    const int*   dst   = (const int*)d_in[1];
    const int*   etype = (const int*)d_in[2];
    const float* norm  = (const float*)d_in[3];
    const float* emb   = (const float*)d_in[4];
    const float* V1    = (const float*)d_in[5];
    const float* comp1 = (const float*)d_in[6];
    const float* bias1 = (const float*)d_in[7];
    const float* V2    = (const float*)d_in[8];
    const float* comp2 = (const float*)d_in[9];
    const float* bias2 = (const float*)d_in[10];
    float* out = (float*)d_out;

    char* w = (char*)d_ws;
    auto alloc = [&](size_t bytes) -> char* {
        char* p = w; w += (bytes + 255) & ~(size_t)255; return p;
    };
    int*      offsets = (int*)alloc((NN + 1) * 4);
    int*      counts  = (int*)alloc(NN * 4);
    int*      cursor  = (int*)alloc(NN * 4);
    int*      tot     = (int*)alloc(SC_B * 4);
    int*      msrc    = (int*)alloc((size_t)EE * 4);
    int*      netn    = (int*)alloc((size_t)EE * 4);
    float*    wedge   = (float*)alloc((size_t)EE * BB * 4);
    ushort_t* Wt1     = (ushort_t*)alloc((size_t)HH * KK * 2);
    ushort_t* Wt2     = (ushort_t*)alloc((size_t)OUTD * KK * 2);
    ushort_t* xb      = (ushort_t*)alloc((size_t)NN * HH * 2);
    ushort_t* h       = (ushort_t*)alloc((size_t)NN * HH * 2);
    size_t used  = (size_t)(w - (char*)d_ws);
    size_t avail = ws_size > used ? ws_size - used : 0;
    int chunkN = (int)(avail / ((size_t)KK * 2));
    chunkN &= ~127;
    if (chunkN < 128) chunkN = 128;
    if (chunkN > NN) chunkN = NN;
    ushort_t* agg = (ushort_t*)w;

    // CSR build + payload sort + weight/emb conversion
    hipMemsetAsync(counts, 0, NN * 4, stream);
    hist_kernel<<<(EE + 255)/256, 256, 0, stream>>>(dst, counts);
    scan_part<<<SC_B, 256, 0, stream>>>(counts, tot);
    scan_tot<<<1, 64, 0, stream>>>(tot);
    scan_final<<<SC_B, 256, 0, stream>>>(counts, tot, offsets, cursor);
    scatter_kernel<<<(EE + 255)/256, 256, 0, stream>>>(dst, src, etype, norm,
                                                       cursor, msrc, netn);
    prep_kernel<<<(N_CONVW + N_EMB + EE + 255)/256, 256, 0, stream>>>(
        V1, V2, emb, netn, comp1, Wt1, Wt2, xb, wedge);

    // layer 1: xb (bf16) -> h (bf16, relu)
    for (int v0 = 0; v0 < NN; v0 += chunkN){
        int vc = (NN - v0 < chunkN) ? (NN - v0) : chunkN;
        agg_kernel<<<(vc + 3)/4, 256, 0, stream>>>(
            xb, msrc, wedge, offsets, agg, v0, vc);
        gemm_kernel<HH, true, true><<<(vc + 127)/128, 512, 0, stream>>>(
            agg, Wt1, bias1, h + (size_t)v0 * HH, vc);
    }
    // rebuild wedge for layer 2, then layer 2: h (bf16) -> out (f32)
    build_w_kernel<<<(EE + 255)/256, 256, 0, stream>>>(netn, comp2, wedge);
    for (int v0 = 0; v0 < NN; v0 += chunkN){
        int vc = (NN - v0 < chunkN) ? (NN - v0) : chunkN;
        agg_kernel<<<(vc + 3)/4, 256, 0, stream>>>(
            h, msrc, wedge, offsets, agg, v0, vc);
        gemm_kernel<OUTD, false, false><<<(vc + 127)/128, 512, 0, stream>>>(
            agg, Wt2, bias2, out + (size_t)v0 * OUTD, vc);
    }
}

// Round 14
// 340.015 us; speedup vs baseline: 1.3565x; 1.3565x over previous
//
#include <hip/hip_runtime.h>
#include <hip/hip_bf16.h>

#define NN 50000
#define EE 600000
#define HH 128
#define OUTD 32
#define RR 64
#define BB 16
#define KK 2048   // BB*HH
#define SC_B ((NN + 1023) / 1024)  // 49 scan chunks
#define N_CONVW ((HH + OUTD) * KK)
#define N_EMB   (NN * HH / 2)
#define CHUNK_CAP 32768   // 134MB agg chunk: stays L3-resident between agg and gemm

typedef short s16x8 __attribute__((ext_vector_type(8)));
typedef float f32x4 __attribute__((ext_vector_type(4)));
typedef float f32x2 __attribute__((ext_vector_type(2)));
typedef unsigned short ushort_t;
typedef unsigned int uint_t;
typedef __attribute__((address_space(3))) uint_t lds_u32;
typedef const __attribute__((address_space(1))) uint_t glb_u32;

__device__ inline ushort_t f_to_bf16(float f){
    __hip_bfloat16 h = __float2bfloat16(f);
    return *reinterpret_cast<ushort_t*>(&h);
}
__device__ inline uint_t pack_bf16x2(float a, float b){
    return (uint_t)f_to_bf16(a) | ((uint_t)f_to_bf16(b) << 16);
}

__global__ void hist_kernel(const int* __restrict__ dst, int* counts){
    int e = blockIdx.x*256 + threadIdx.x;
    if (e < EE) atomicAdd(&counts[dst[e]], 1);
}

// ---- hierarchical scan: chunk totals -> scan totals -> final ----
__global__ void scan_part(const int* __restrict__ counts, int* __restrict__ tot){
    int b = blockIdx.x, t = threadIdx.x;
    int i0 = b*1024 + t*4;
    int s = 0;
    if (i0 + 3 < NN){
        int4 v = *reinterpret_cast<const int4*>(&counts[i0]);
        s = v.x + v.y + v.z + v.w;
    } else {
        for (int j = 0; j < 4; j++) if (i0 + j < NN) s += counts[i0 + j];
    }
    #pragma unroll
    for (int off = 32; off; off >>= 1) s += __shfl_xor(s, off, 64);
    __shared__ int ws[4];
    if ((t & 63) == 0) ws[t >> 6] = s;
    __syncthreads();
    if (t == 0) tot[b] = ws[0] + ws[1] + ws[2] + ws[3];
}

__global__ void scan_tot(int* tot){  // 1 block, 64 threads (SC_B <= 64)
    int t = threadIdx.x;
    int v = (t < SC_B) ? tot[t] : 0;
    int x = v;
    #pragma unroll
    for (int off = 1; off < 64; off <<= 1){
        int y = __shfl_up(x, off, 64);
        if (t >= off) x += y;
    }
    if (t < SC_B) tot[t] = x - v;  // exclusive base per chunk
}

__global__ void scan_final(const int* __restrict__ counts, const int* __restrict__ tot,
                           int* __restrict__ offsets, int* __restrict__ cursor){
    int b = blockIdx.x, t = threadIdx.x, lane = t & 63, wv = t >> 6;
    int i0 = b*1024 + t*4;
    int v[4]; int s = 0;
    #pragma unroll
    for (int j = 0; j < 4; j++){ v[j] = (i0 + j < NN) ? counts[i0 + j] : 0; s += v[j]; }
    int x = s;
    #pragma unroll
    for (int off = 1; off < 64; off <<= 1){
        int y = __shfl_up(x, off, 64);
        if (lane >= off) x += y;
    }
    __shared__ int ws[4];
    if (lane == 63) ws[wv] = x;
    __syncthreads();
    int pre = tot[b];
    for (int i = 0; i < wv; i++) pre += ws[i];
    int run = pre + x - s;  // exclusive start of this thread's 4 elems
    #pragma unroll
    for (int j = 0; j < 4; j++){
        if (i0 + j < NN){
            cursor[i0 + j] = run;
            offsets[i0 + j + 1] = run + v[j];
        }
        run += v[j];
    }
    if (b == 0 && t == 0) offsets[0] = 0;
}

// scatter dst-sorted edge payload: msrc[r] = src row, netn[r] = norm_bits|etype
// (etype stuffed into norm's 6 low mantissa bits: <=7.5e-6 relative error)
__global__ void scatter_kernel(const int* __restrict__ dst, const int* __restrict__ src,
                               const int* __restrict__ etype, const float* __restrict__ norm,
                               int* cursor, int* __restrict__ msrc, int* __restrict__ netn){
    int e = blockIdx.x*256 + threadIdx.x;
    if (e >= EE) return;
    int d = dst[e];
    int r = atomicAdd(&cursor[d], 1);
    msrc[r] = src[e];
    netn[r] = (__float_as_int(norm[e]) & ~63) | etype[e];
}

// fused prologue: Wt1/Wt2 transpose-convert + emb->bf16
__global__ void prep_kernel(const float* __restrict__ V1, const float* __restrict__ V2,
                            const float* __restrict__ emb,
                            ushort_t* __restrict__ Wt1, ushort_t* __restrict__ Wt2,
                            ushort_t* __restrict__ xb){
    int i = blockIdx.x*256 + threadIdx.x;
    if (i < HH*KK){
        int o = i / KK, k = i % KK;
        Wt1[i] = f_to_bf16(V1[(size_t)k*HH + o]);
    } else if (i < N_CONVW){
        int j = i - HH*KK;
        int o = j / KK, k = j % KK;
        Wt2[j] = f_to_bf16(V2[(size_t)k*OUTD + o]);
    } else if (i < N_CONVW + N_EMB){
        int j = i - N_CONVW;
        float2 f = *reinterpret_cast<const float2*>(emb + 2*(size_t)j);
        *reinterpret_cast<uint_t*>(xb + 2*(size_t)j) = pack_bf16x2(f.x, f.y);
    }
}

// Aggregate: 1 node per wave, 4 waves/block, no LDS/barriers. Per <=64-edge
// chunk: metas in lane registers; 8-deep register ring of coalesced 256B
// x-row loads; consume = 16 v_pk_fma_f32 per edge (dual-f32; comp pairs come
// as consecutive SGPRs from the scalar cache; op_sel broadcasts the x feat).
__global__ __launch_bounds__(256, 8) void agg_kernel(
    const ushort_t* __restrict__ xin, const int* __restrict__ msrc,
    const int* __restrict__ netn, const int* __restrict__ offsets,
    const float* __restrict__ comp, ushort_t* __restrict__ agg,
    int v0, int vc)
{
    int w = threadIdx.x >> 6, lane = threadIdx.x & 63;
    int v = v0 + blockIdx.x*4 + w;
    if (v >= v0 + vc) return;
    int p0 = offsets[v];
    int dd = offsets[v+1] - p0;
    const uint_t* xrow = reinterpret_cast<const uint_t*>(xin);  // row r at xrow + r*64

    // accA[bp] = {agg[2bp], agg[2bp+1]} at feat 2*lane; accB at feat 2*lane+1
    f32x2 accA[8], accB[8];
    #pragma unroll
    for (int bp = 0; bp < 8; bp++){
        accA[bp].x = 0.f; accA[bp].y = 0.f;
        accB[bp].x = 0.f; accB[bp].y = 0.f;
    }

    for (int c0 = 0; c0 < dd; c0 += 64){
        int nc = min(64, dd - c0);
        int li = p0 + c0 + min(lane, nc - 1);
        int mp = msrc[li];      // lane e: src row of edge e
        int nr = netn[li];      // lane e: norm bits | etype
        uint_t xr[8];
        #pragma unroll
        for (int j = 0; j < 8; ++j){
            int sr = __builtin_amdgcn_readlane(mp, min(j, nc - 1));
            xr[j] = xrow[(size_t)sr*64 + lane];
        }
        for (int eb = 0; eb < nc; eb += 8){
            #pragma unroll
            for (int j = 0; j < 8; ++j){
                int e = eb + j;                       // uniform
                int ec = min(e, nc - 1);
                int nb = __builtin_amdgcn_readlane(nr, ec);
                int et = nb & 63;
                float nw = (e < nc) ? __int_as_float(nb & ~63) : 0.f;
                uint_t u = xr[j];
                f32x2 xs;
                xs.x = __uint_as_float(u << 16) * nw;         // feat 2*lane
                xs.y = __uint_as_float(u & 0xffff0000u) * nw; // feat 2*lane+1
                int en = e + 8;
                if (en < nc){                          // uniform branch: refill ring
                    int srn = __builtin_amdgcn_readlane(mp, en);
                    xr[j] = xrow[(size_t)srn*64 + lane];
                }
                const f32x2* cp = reinterpret_cast<const f32x2*>(comp + et*BB);
                #pragma unroll
                for (int bp = 0; bp < 8; bp++){
                    f32x2 c2 = cp[bp];   // {c[2bp], c[2bp+1]} consecutive SGPRs
                    asm("v_pk_fma_f32 %0, %1, %2, %0 op_sel:[0,0,0] op_sel_hi:[1,0,1]"
                        : "+v"(accA[bp]) : "s"(c2), "v"(xs));
                    asm("v_pk_fma_f32 %0, %1, %2, %0 op_sel:[0,1,0] op_sel_hi:[1,1,1]"
                        : "+v"(accB[bp]) : "s"(c2), "v"(xs));
                }
            }
        }
    }
    // store agg row (bf16x2 packed, coalesced 256B per basis)
    uint_t* arow = reinterpret_cast<uint_t*>(agg) + (size_t)(v - v0)*1024 + lane;
    #pragma unroll
    for (int b = 0; b < BB; b++)
        arow[b*64] = pack_bf16x2(accA[b>>1][b&1], accB[b>>1][b&1]);
}

// GEMM: C[m, o] = sum_k A[m,k] * Wt[o,k] (+bias, opt relu). 128xBN tile, 512
// thr. Double-buffered global_load_lds staging w/ chunk-XOR swizzle; COUNTED
// vmcnt at a raw s_barrier (prefetch loads stay in flight across the barrier).
template<int BN, bool RELU, bool OUT_BF16>
__global__ __launch_bounds__(512, 4) void gemm_kernel(
    const ushort_t* __restrict__ A, const ushort_t* __restrict__ Wt,
    const float* __restrict__ bias, void* __restrict__ yout, int vc)
{
    __shared__ __align__(16) char Ald[2][128*128];
    __shared__ __align__(16) char Bld[2][BN*128];
    constexpr int RT = (BN == 128) ? 2 : 1;
    constexpr int CT = (BN == 128) ? 4 : 2;
    constexpr int NT = KK / 64;
    int tid = threadIdx.x, lane = tid & 63, lane15 = lane & 15;
    int w = tid >> 6;
    int wrbase = (BN == 128) ? (w >> 1)*32 : w*16;
    int wcbase = (BN == 128) ? (w & 1)*64 : 0;
    int m0 = blockIdx.x * 128;

    int rl = lane >> 3, jl = lane & 7;
    int ra0 = w*2*8 + rl,  ra1 = (w*2+1)*8 + rl;
    const ushort_t* agp0 = A + (size_t)(m0 + min(ra0, vc-1))*KK + ((jl ^ (ra0 & 7))*8);
    const ushort_t* agp1 = A + (size_t)(m0 + min(ra1, vc-1))*KK + ((jl ^ (ra1 & 7))*8);
    const ushort_t* bgp0;
    const ushort_t* bgp1;
    if (BN == 128){
        bgp0 = Wt + (size_t)ra0*KK + ((jl ^ (ra0 & 7))*8);
        bgp1 = Wt + (size_t)ra1*KK + ((jl ^ (ra1 & 7))*8);
    } else {
        int rb = w*8 + rl;  // valid for w<4
        bgp0 = Wt + (size_t)min(rb, BN-1)*KK + ((jl ^ (rb & 7))*8);
        bgp1 = nullptr;
    }

    auto stage = [&](int buf){
        __builtin_amdgcn_global_load_lds((glb_u32*)agp0,
            (lds_u32*)(&Ald[buf][(w*2+0)*1024]), 16, 0, 0);
        __builtin_amdgcn_global_load_lds((glb_u32*)agp1,
            (lds_u32*)(&Ald[buf][(w*2+1)*1024]), 16, 0, 0);
        agp0 += 64; agp1 += 64;
        if constexpr (BN == 128){
            __builtin_amdgcn_global_load_lds((glb_u32*)bgp0,
                (lds_u32*)(&Bld[buf][(w*2+0)*1024]), 16, 0, 0);
            __builtin_amdgcn_global_load_lds((glb_u32*)bgp1,
                (lds_u32*)(&Bld[buf][(w*2+1)*1024]), 16, 0, 0);
            bgp0 += 64; bgp1 += 64;
        } else {
            if (w < 4){
                __builtin_amdgcn_global_load_lds((glb_u32*)bgp0,
                    (lds_u32*)(&Bld[buf][w*1024]), 16, 0, 0);
                bgp0 += 64;
            }
        }
    };

    f32x4 acc[RT][CT];
    #pragma unroll
    for (int t = 0; t < RT; t++)
        #pragma unroll
        for (int ct = 0; ct < CT; ct++)
            #pragma unroll
            for (int j = 0; j < 4; j++) acc[t][ct][j] = 0.f;

    auto compute = [&](int buf){
        #pragma unroll
        for (int ks = 0; ks < 2; ks++){
            int csw = (ks*4 + (lane >> 4)) ^ (lane15 & 7);
            #pragma unroll
            for (int t = 0; t < RT; t++){
                int arow = wrbase + t*16 + lane15;
                s16x8 a = *reinterpret_cast<const s16x8*>(&Ald[buf][arow*128 + csw*16]);
                #pragma unroll
                for (int ct = 0; ct < CT; ct++){
                    int brow = wcbase + ct*16 + lane15;
                    s16x8 b = *reinterpret_cast<const s16x8*>(&Bld[buf][brow*128 + csw*16]);
                    acc[t][ct] = __builtin_amdgcn_mfma_f32_16x16x32_bf16(a, b, acc[t][ct], 0,0,0);
                }
            }
        }
    };

    stage(0);
    for (int t = 0; t < NT; ++t){
        int cur = t & 1;
        if (t + 1 < NT){
            stage(cur ^ 1);
            if (BN == 128)       asm volatile("s_waitcnt vmcnt(4)" ::: "memory");
            else if (w < 4)      asm volatile("s_waitcnt vmcnt(3)" ::: "memory");
            else                 asm volatile("s_waitcnt vmcnt(2)" ::: "memory");
        } else {
            asm volatile("s_waitcnt vmcnt(0)" ::: "memory");
        }
        __builtin_amdgcn_s_barrier();
        __builtin_amdgcn_sched_barrier(0);
        compute(cur);
        __builtin_amdgcn_s_barrier();
    }

    #pragma unroll
    for (int t = 0; t < RT; t++){
        int rb = m0 + wrbase + t*16 + ((lane >> 4) << 2);
        #pragma unroll
        for (int ct = 0; ct < CT; ct++){
            int col = wcbase + ct*16 + lane15;
            float bv = bias[col];
            #pragma unroll
            for (int r = 0; r < 4; r++){
                int row = rb + r;
                if (row < vc){
                    float val = acc[t][ct][r] + bv;
                    if (RELU) val = fmaxf(val, 0.f);
                    if (OUT_BF16)
                        reinterpret_cast<ushort_t*>(yout)[(size_t)row*BN + col] = f_to_bf16(val);
                    else
                        reinterpret_cast<float*>(yout)[(size_t)row*BN + col] = val;
                }
            }
        }
    }
}

extern "C" void kernel_launch(void* const* d_in, const int* in_sizes, int n_in,
                              void* d_out, int out_size, void* d_ws, size_t ws_size,
                              hipStream_t stream){
    const int*   src   = (const int*)d_in[0];
    const int*   dst   = (const int*)d_in[1];
    const int*   etype = (const int*)d_in[2];
    const float* norm  = (const float*)d_in[3];
    const float* emb   = (const float*)d_in[4];
    const float* V1    = (const float*)d_in[5];
    const float* comp1 = (const float*)d_in[6];
    const float* bias1 = (const float*)d_in[7];
    const float* V2    = (const float*)d_in[8];
    const float* comp2 = (const float*)d_in[9];
    const float* bias2 = (const float*)d_in[10];
    float* out = (float*)d_out;

    char* w = (char*)d_ws;
    auto alloc = [&](size_t bytes) -> char* {
        char* p = w; w += (bytes + 255) & ~(size_t)255; return p;
    };
    int*      offsets = (int*)alloc((NN + 1) * 4);
    int*      counts  = (int*)alloc(NN * 4);
    int*      cursor  = (int*)alloc(NN * 4);
    int*      tot     = (int*)alloc(SC_B * 4);
    int*      msrc    = (int*)alloc((size_t)EE * 4);
    int*      netn    = (int*)alloc((size_t)EE * 4);
    ushort_t* Wt1     = (ushort_t*)alloc((size_t)HH * KK * 2);
    ushort_t* Wt2     = (ushort_t*)alloc((size_t)OUTD * KK * 2);
    ushort_t* xb      = (ushort_t*)alloc((size_t)NN * HH * 2);
    ushort_t* h       = (ushort_t*)alloc((size_t)NN * HH * 2);
    size_t used  = (size_t)(w - (char*)d_ws);
    size_t avail = ws_size > used ? ws_size - used : 0;
    int chunkN = (int)(avail / ((size_t)KK * 2));
    chunkN &= ~127;
    if (chunkN < 128) chunkN = 128;
    if (chunkN > CHUNK_CAP) chunkN = CHUNK_CAP;   // L3 blocking: agg chunk <= 134MB
    if (chunkN > NN) chunkN = NN;
    ushort_t* agg = (ushort_t*)w;

    // CSR build + payload sort + weight/emb conversion
    hipMemsetAsync(counts, 0, NN * 4, stream);
    hist_kernel<<<(EE + 255)/256, 256, 0, stream>>>(dst, counts);
    scan_part<<<SC_B, 256, 0, stream>>>(counts, tot);
    scan_tot<<<1, 64, 0, stream>>>(tot);
    scan_final<<<SC_B, 256, 0, stream>>>(counts, tot, offsets, cursor);
    scatter_kernel<<<(EE + 255)/256, 256, 0, stream>>>(dst, src, etype, norm,
                                                       cursor, msrc, netn);
    prep_kernel<<<(N_CONVW + N_EMB + 255)/256, 256, 0, stream>>>(
        V1, V2, emb, Wt1, Wt2, xb);

    // layer 1: xb (bf16) -> h (bf16, relu)
    for (int v0 = 0; v0 < NN; v0 += chunkN){
        int vc = (NN - v0 < chunkN) ? (NN - v0) : chunkN;
        agg_kernel<<<(vc + 3)/4, 256, 0, stream>>>(
            xb, msrc, netn, offsets, comp1, agg, v0, vc);
        gemm_kernel<HH, true, true><<<(vc + 127)/128, 512, 0, stream>>>(
            agg, Wt1, bias1, h + (size_t)v0 * HH, vc);
    }
    // layer 2: h (bf16) -> out (f32)
    for (int v0 = 0; v0 < NN; v0 += chunkN){
        int vc = (NN - v0 < chunkN) ? (NN - v0) : chunkN;
        agg_kernel<<<(vc + 3)/4, 256, 0, stream>>>(
            h, msrc, netn, offsets, comp2, agg, v0, vc);
        gemm_kernel<OUTD, false, false><<<(vc + 127)/128, 512, 0, stream>>>(
            agg, Wt2, bias2, out + (size_t)v0 * OUTD, vc);
    }
}

// Round 15
// 301.831 us; speedup vs baseline: 1.5281x; 1.1265x over previous
//
#include <hip/hip_runtime.h>
#include <hip/hip_bf16.h>

#define NN 50000
#define EE 600000
#define HH 128
#define OUTD 32
#define RR 64
#define BB 16
#define KK 2048   // BB*HH
#define SC_B ((NN + 1023) / 1024)  // 49 scan chunks
#define N_CONVW ((HH + OUTD) * KK)
#define N_EMB   (NN * HH / 2)

typedef short s16x8 __attribute__((ext_vector_type(8)));
typedef float f32x4 __attribute__((ext_vector_type(4)));
typedef float f32x2 __attribute__((ext_vector_type(2)));
typedef unsigned short ushort_t;
typedef unsigned int uint_t;
typedef __attribute__((address_space(3))) uint_t lds_u32;
typedef const __attribute__((address_space(1))) uint_t glb_u32;

__device__ inline ushort_t f_to_bf16(float f){
    __hip_bfloat16 h = __float2bfloat16(f);
    return *reinterpret_cast<ushort_t*>(&h);
}
__device__ inline uint_t pack_bf16x2(float a, float b){
    return (uint_t)f_to_bf16(a) | ((uint_t)f_to_bf16(b) << 16);
}

__global__ void hist_kernel(const int* __restrict__ dst, int* counts){
    int e = blockIdx.x*256 + threadIdx.x;
    if (e < EE) atomicAdd(&counts[dst[e]], 1);
}

// ---- hierarchical scan: chunk totals -> scan totals -> final ----
__global__ void scan_part(const int* __restrict__ counts, int* __restrict__ tot){
    int b = blockIdx.x, t = threadIdx.x;
    int i0 = b*1024 + t*4;
    int s = 0;
    if (i0 + 3 < NN){
        int4 v = *reinterpret_cast<const int4*>(&counts[i0]);
        s = v.x + v.y + v.z + v.w;
    } else {
        for (int j = 0; j < 4; j++) if (i0 + j < NN) s += counts[i0 + j];
    }
    #pragma unroll
    for (int off = 32; off; off >>= 1) s += __shfl_xor(s, off, 64);
    __shared__ int ws[4];
    if ((t & 63) == 0) ws[t >> 6] = s;
    __syncthreads();
    if (t == 0) tot[b] = ws[0] + ws[1] + ws[2] + ws[3];
}

__global__ void scan_tot(int* tot){  // 1 block, 64 threads (SC_B <= 64)
    int t = threadIdx.x;
    int v = (t < SC_B) ? tot[t] : 0;
    int x = v;
    #pragma unroll
    for (int off = 1; off < 64; off <<= 1){
        int y = __shfl_up(x, off, 64);
        if (t >= off) x += y;
    }
    if (t < SC_B) tot[t] = x - v;  // exclusive base per chunk
}

__global__ void scan_final(const int* __restrict__ counts, const int* __restrict__ tot,
                           int* __restrict__ offsets, int* __restrict__ cursor){
    int b = blockIdx.x, t = threadIdx.x, lane = t & 63, wv = t >> 6;
    int i0 = b*1024 + t*4;
    int v[4]; int s = 0;
    #pragma unroll
    for (int j = 0; j < 4; j++){ v[j] = (i0 + j < NN) ? counts[i0 + j] : 0; s += v[j]; }
    int x = s;
    #pragma unroll
    for (int off = 1; off < 64; off <<= 1){
        int y = __shfl_up(x, off, 64);
        if (lane >= off) x += y;
    }
    __shared__ int ws[4];
    if (lane == 63) ws[wv] = x;
    __syncthreads();
    int pre = tot[b];
    for (int i = 0; i < wv; i++) pre += ws[i];
    int run = pre + x - s;  // exclusive start of this thread's 4 elems
    #pragma unroll
    for (int j = 0; j < 4; j++){
        if (i0 + j < NN){
            cursor[i0 + j] = run;
            offsets[i0 + j + 1] = run + v[j];
        }
        run += v[j];
    }
    if (b == 0 && t == 0) offsets[0] = 0;
}

// scatter dst-sorted edge payload: msrc[r] = src row, netn[r] = norm_bits|etype
// (etype stuffed into norm's 6 low mantissa bits: <=7.5e-6 relative error)
__global__ void scatter_kernel(const int* __restrict__ dst, const int* __restrict__ src,
                               const int* __restrict__ etype, const float* __restrict__ norm,
                               int* cursor, int* __restrict__ msrc, int* __restrict__ netn){
    int e = blockIdx.x*256 + threadIdx.x;
    if (e >= EE) return;
    int d = dst[e];
    int r = atomicAdd(&cursor[d], 1);
    msrc[r] = src[e];
    netn[r] = (__float_as_int(norm[e]) & ~63) | etype[e];
}

// fused prologue: Wt1/Wt2 transpose-convert + emb->bf16
__global__ void prep_kernel(const float* __restrict__ V1, const float* __restrict__ V2,
                            const float* __restrict__ emb,
                            ushort_t* __restrict__ Wt1, ushort_t* __restrict__ Wt2,
                            ushort_t* __restrict__ xb){
    int i = blockIdx.x*256 + threadIdx.x;
    if (i < HH*KK){
        int o = i / KK, k = i % KK;
        Wt1[i] = f_to_bf16(V1[(size_t)k*HH + o]);
    } else if (i < N_CONVW){
        int j = i - HH*KK;
        int o = j / KK, k = j % KK;
        Wt2[j] = f_to_bf16(V2[(size_t)k*OUTD + o]);
    } else if (i < N_CONVW + N_EMB){
        int j = i - N_CONVW;
        float2 f = *reinterpret_cast<const float2*>(emb + 2*(size_t)j);
        *reinterpret_cast<uint_t*>(xb + 2*(size_t)j) = pack_bf16x2(f.x, f.y);
    }
}

// Aggregate: 1 node per wave, 4 waves/block, no LDS/barriers. Per <=64-edge
// chunk: metas in lane registers; 8-deep register ring of coalesced 256B
// x-row loads; consume = 16 v_pk_fma_f32 per edge (dual-f32; comp pairs come
// as consecutive SGPRs from the scalar cache; op_sel broadcasts the x feat).
// launch_bounds (256,6): 85-VGPR budget so ring+accs live in arch VGPRs.
__global__ __launch_bounds__(256, 6) void agg_kernel(
    const ushort_t* __restrict__ xin, const int* __restrict__ msrc,
    const int* __restrict__ netn, const int* __restrict__ offsets,
    const float* __restrict__ comp, ushort_t* __restrict__ agg,
    int v0, int vc)
{
    int w = threadIdx.x >> 6, lane = threadIdx.x & 63;
    int v = v0 + blockIdx.x*4 + w;
    if (v >= v0 + vc) return;
    int p0 = offsets[v];
    int dd = offsets[v+1] - p0;
    const uint_t* xrow = reinterpret_cast<const uint_t*>(xin);  // row r at xrow + r*64

    // accA[bp] = {agg[2bp], agg[2bp+1]} at feat 2*lane; accB at feat 2*lane+1
    f32x2 accA[8], accB[8];
    #pragma unroll
    for (int bp = 0; bp < 8; bp++){
        accA[bp].x = 0.f; accA[bp].y = 0.f;
        accB[bp].x = 0.f; accB[bp].y = 0.f;
    }

    for (int c0 = 0; c0 < dd; c0 += 64){
        int nc = min(64, dd - c0);
        int li = p0 + c0 + min(lane, nc - 1);
        int mp = msrc[li];      // lane e: src row of edge e
        int nr = netn[li];      // lane e: norm bits | etype
        uint_t xr[8];
        #pragma unroll
        for (int j = 0; j < 8; ++j){
            int sr = __builtin_amdgcn_readlane(mp, min(j, nc - 1));
            xr[j] = xrow[(size_t)sr*64 + lane];
        }
        for (int eb = 0; eb < nc; eb += 8){
            #pragma unroll
            for (int j = 0; j < 8; ++j){
                int e = eb + j;                       // uniform
                int ec = min(e, nc - 1);
                int nb = __builtin_amdgcn_readlane(nr, ec);
                int et = nb & 63;
                float nw = (e < nc) ? __int_as_float(nb & ~63) : 0.f;
                uint_t u = xr[j];
                f32x2 xs;
                xs.x = __uint_as_float(u << 16) * nw;         // feat 2*lane
                xs.y = __uint_as_float(u & 0xffff0000u) * nw; // feat 2*lane+1
                int en = e + 8;
                if (en < nc){                          // uniform branch: refill ring
                    int srn = __builtin_amdgcn_readlane(mp, en);
                    xr[j] = xrow[(size_t)srn*64 + lane];
                }
                const f32x2* cp = reinterpret_cast<const f32x2*>(comp + et*BB);
                #pragma unroll
                for (int bp = 0; bp < 8; bp++){
                    f32x2 c2 = cp[bp];   // {c[2bp], c[2bp+1]} consecutive SGPRs
                    asm("v_pk_fma_f32 %0, %1, %2, %0 op_sel:[0,0,0] op_sel_hi:[1,0,1]"
                        : "+v"(accA[bp]) : "s"(c2), "v"(xs));
                    asm("v_pk_fma_f32 %0, %1, %2, %0 op_sel:[0,1,0] op_sel_hi:[1,1,1]"
                        : "+v"(accB[bp]) : "s"(c2), "v"(xs));
                }
            }
        }
    }
    // store agg row: v_cvt_pk_bf16_f32 packs {accA -> lo, accB -> hi} in 1 instr
    uint_t* arow = reinterpret_cast<uint_t*>(agg) + (size_t)(v - v0)*1024 + lane;
    #pragma unroll
    for (int b = 0; b < BB; b++){
        uint_t pk;
        asm("v_cvt_pk_bf16_f32 %0, %1, %2"
            : "=v"(pk) : "v"(accA[b>>1][b&1]), "v"(accB[b>>1][b&1]));
        arow[b*64] = pk;
    }
}

// GEMM: C[m, o] = sum_k A[m,k] * Wt[o,k] (+bias, opt relu). 128xBN tile, 512
// thr. Double-buffered global_load_lds staging w/ chunk-XOR swizzle; COUNTED
// vmcnt at a raw s_barrier (prefetch loads stay in flight across the barrier).
template<int BN, bool RELU, bool OUT_BF16>
__global__ __launch_bounds__(512, 4) void gemm_kernel(
    const ushort_t* __restrict__ A, const ushort_t* __restrict__ Wt,
    const float* __restrict__ bias, void* __restrict__ yout, int vc)
{
    __shared__ __align__(16) char Ald[2][128*128];
    __shared__ __align__(16) char Bld[2][BN*128];
    constexpr int RT = (BN == 128) ? 2 : 1;
    constexpr int CT = (BN == 128) ? 4 : 2;
    constexpr int NT = KK / 64;
    int tid = threadIdx.x, lane = tid & 63, lane15 = lane & 15;
    int w = tid >> 6;
    int wrbase = (BN == 128) ? (w >> 1)*32 : w*16;
    int wcbase = (BN == 128) ? (w & 1)*64 : 0;
    int m0 = blockIdx.x * 128;

    int rl = lane >> 3, jl = lane & 7;
    int ra0 = w*2*8 + rl,  ra1 = (w*2+1)*8 + rl;
    const ushort_t* agp0 = A + (size_t)(m0 + min(ra0, vc-1))*KK + ((jl ^ (ra0 & 7))*8);
    const ushort_t* agp1 = A + (size_t)(m0 + min(ra1, vc-1))*KK + ((jl ^ (ra1 & 7))*8);
    const ushort_t* bgp0;
    const ushort_t* bgp1;
    if (BN == 128){
        bgp0 = Wt + (size_t)ra0*KK + ((jl ^ (ra0 & 7))*8);
        bgp1 = Wt + (size_t)ra1*KK + ((jl ^ (ra1 & 7))*8);
    } else {
        int rb = w*8 + rl;  // valid for w<4
        bgp0 = Wt + (size_t)min(rb, BN-1)*KK + ((jl ^ (rb & 7))*8);
        bgp1 = nullptr;
    }

    auto stage = [&](int buf){
        __builtin_amdgcn_global_load_lds((glb_u32*)agp0,
            (lds_u32*)(&Ald[buf][(w*2+0)*1024]), 16, 0, 0);
        __builtin_amdgcn_global_load_lds((glb_u32*)agp1,
            (lds_u32*)(&Ald[buf][(w*2+1)*1024]), 16, 0, 0);
        agp0 += 64; agp1 += 64;
        if constexpr (BN == 128){
            __builtin_amdgcn_global_load_lds((glb_u32*)bgp0,
                (lds_u32*)(&Bld[buf][(w*2+0)*1024]), 16, 0, 0);
            __builtin_amdgcn_global_load_lds((glb_u32*)bgp1,
                (lds_u32*)(&Bld[buf][(w*2+1)*1024]), 16, 0, 0);
            bgp0 += 64; bgp1 += 64;
        } else {
            if (w < 4){
                __builtin_amdgcn_global_load_lds((glb_u32*)bgp0,
                    (lds_u32*)(&Bld[buf][w*1024]), 16, 0, 0);
                bgp0 += 64;
            }
        }
    };

    f32x4 acc[RT][CT];
    #pragma unroll
    for (int t = 0; t < RT; t++)
        #pragma unroll
        for (int ct = 0; ct < CT; ct++)
            #pragma unroll
            for (int j = 0; j < 4; j++) acc[t][ct][j] = 0.f;

    auto compute = [&](int buf){
        #pragma unroll
        for (int ks = 0; ks < 2; ks++){
            int csw = (ks*4 + (lane >> 4)) ^ (lane15 & 7);
            #pragma unroll
            for (int t = 0; t < RT; t++){
                int arow = wrbase + t*16 + lane15;
                s16x8 a = *reinterpret_cast<const s16x8*>(&Ald[buf][arow*128 + csw*16]);
                #pragma unroll
                for (int ct = 0; ct < CT; ct++){
                    int brow = wcbase + ct*16 + lane15;
                    s16x8 b = *reinterpret_cast<const s16x8*>(&Bld[buf][brow*128 + csw*16]);
                    acc[t][ct] = __builtin_amdgcn_mfma_f32_16x16x32_bf16(a, b, acc[t][ct], 0,0,0);
                }
            }
        }
    };

    stage(0);
    for (int t = 0; t < NT; ++t){
        int cur = t & 1;
        if (t + 1 < NT){
            stage(cur ^ 1);
            if (BN == 128)       asm volatile("s_waitcnt vmcnt(4)" ::: "memory");
            else if (w < 4)      asm volatile("s_waitcnt vmcnt(3)" ::: "memory");
            else                 asm volatile("s_waitcnt vmcnt(2)" ::: "memory");
        } else {
            asm volatile("s_waitcnt vmcnt(0)" ::: "memory");
        }
        __builtin_amdgcn_s_barrier();
        __builtin_amdgcn_sched_barrier(0);
        compute(cur);
        __builtin_amdgcn_s_barrier();
    }

    #pragma unroll
    for (int t = 0; t < RT; t++){
        int rb = m0 + wrbase + t*16 + ((lane >> 4) << 2);
        #pragma unroll
        for (int ct = 0; ct < CT; ct++){
            int col = wcbase + ct*16 + lane15;
            float bv = bias[col];
            #pragma unroll
            for (int r = 0; r < 4; r++){
                int row = rb + r;
                if (row < vc){
                    float val = acc[t][ct][r] + bv;
                    if (RELU) val = fmaxf(val, 0.f);
                    if (OUT_BF16)
                        reinterpret_cast<ushort_t*>(yout)[(size_t)row*BN + col] = f_to_bf16(val);
                    else
                        reinterpret_cast<float*>(yout)[(size_t)row*BN + col] = val;
                }
            }
        }
    }
}

extern "C" void kernel_launch(void* const* d_in, const int* in_sizes, int n_in,
                              void* d_out, int out_size, void* d_ws, size_t ws_size,
                              hipStream_t stream){
    const int*   src   = (const int*)d_in[0];
    const int*   dst   = (const int*)d_in[1];
    const int*   etype = (const int*)d_in[2];
    const float* norm  = (const float*)d_in[3];
    const float* emb   = (const float*)d_in[4];
    const float* V1    = (const float*)d_in[5];
    const float* comp1 = (const float*)d_in[6];
    const float* bias1 = (const float*)d_in[7];
    const float* V2    = (const float*)d_in[8];
    const float* comp2 = (const float*)d_in[9];
    const float* bias2 = (const float*)d_in[10];
    float* out = (float*)d_out;

    char* w = (char*)d_ws;
    auto alloc = [&](size_t bytes) -> char* {
        char* p = w; w += (bytes + 255) & ~(size_t)255; return p;
    };
    int*      offsets = (int*)alloc((NN + 1) * 4);
    int*      counts  = (int*)alloc(NN * 4);
    int*      cursor  = (int*)alloc(NN * 4);
    int*      tot     = (int*)alloc(SC_B * 4);
    int*      msrc    = (int*)alloc((size_t)EE * 4);
    int*      netn    = (int*)alloc((size_t)EE * 4);
    ushort_t* Wt1     = (ushort_t*)alloc((size_t)HH * KK * 2);
    ushort_t* Wt2     = (ushort_t*)alloc((size_t)OUTD * KK * 2);
    ushort_t* xb      = (ushort_t*)alloc((size_t)NN * HH * 2);
    ushort_t* h       = (ushort_t*)alloc((size_t)NN * HH * 2);
    size_t used  = (size_t)(w - (char*)d_ws);
    size_t avail = ws_size > used ? ws_size - used : 0;
    int chunkN = (int)(avail / ((size_t)KK * 2));
    chunkN &= ~127;
    if (chunkN < 128) chunkN = 128;
    if (chunkN > NN) chunkN = NN;
    ushort_t* agg = (ushort_t*)w;

    // CSR build + payload sort + weight/emb conversion
    hipMemsetAsync(counts, 0, NN * 4, stream);
    hist_kernel<<<(EE + 255)/256, 256, 0, stream>>>(dst, counts);
    scan_part<<<SC_B, 256, 0, stream>>>(counts, tot);
    scan_tot<<<1, 64, 0, stream>>>(tot);
    scan_final<<<SC_B, 256, 0, stream>>>(counts, tot, offsets, cursor);
    scatter_kernel<<<(EE + 255)/256, 256, 0, stream>>>(dst, src, etype, norm,
                                                       cursor, msrc, netn);
    prep_kernel<<<(N_CONVW + N_EMB + 255)/256, 256, 0, stream>>>(
        V1, V2, emb, Wt1, Wt2, xb);

    // layer 1: xb (bf16) -> h (bf16, relu)
    for (int v0 = 0; v0 < NN; v0 += chunkN){
        int vc = (NN - v0 < chunkN) ? (NN - v0) : chunkN;
        agg_kernel<<<(vc + 3)/4, 256, 0, stream>>>(
            xb, msrc, netn, offsets, comp1, agg, v0, vc);
        gemm_kernel<HH, true, true><<<(vc + 127)/128, 512, 0, stream>>>(
            agg, Wt1, bias1, h + (size_t)v0 * HH, vc);
    }
    // layer 2: h (bf16) -> out (f32)
    for (int v0 = 0; v0 < NN; v0 += chunkN){
        int vc = (NN - v0 < chunkN) ? (NN - v0) : chunkN;
        agg_kernel<<<(vc + 3)/4, 256, 0, stream>>>(
            h, msrc, netn, offsets, comp2, agg, v0, vc);
        gemm_kernel<OUTD, false, false><<<(vc + 127)/128, 512, 0, stream>>>(
            agg, Wt2, bias2, out + (size_t)v0 * OUTD, vc);
    }
}